// Round 1
// baseline (441.360 us; speedup 1.0000x reference)
//
#include <hip/hip_runtime.h>
#include <hip/hip_bf16.h>

#define T_TOKENS 4096
#define HID 1024
#define INTER 2048
#define NEXP 8
#define TOPK 2
#define RTOT (T_TOKENS * TOPK) /* 8192 */
#define BM 128
#define BN 128
#define BK 64
#define MAXTILES (RTOT / BM + NEXP) /* 72 */

typedef __attribute__((ext_vector_type(8))) short bf16x8;
typedef __attribute__((ext_vector_type(4))) float f32x4;

__device__ __forceinline__ unsigned short f2bf(float f) {
  union { float f; unsigned u; } v; v.f = f;
  unsigned u = v.u;
  return (unsigned short)((u + 0x7FFFu + ((u >> 16) & 1u)) >> 16);
}

// byte offset in a [128 rows][64 bf16] LDS tile, XOR-swizzled at 16B granularity
__device__ __forceinline__ int swz(int row, int kb) {
  return row * 128 + (kb ^ ((row & 7) << 4));
}

// ---------------- routing ----------------
__global__ void k_route(const float* __restrict__ logits, int* counts,
                        int* pe, float* pw) {
  int t = blockIdx.x * blockDim.x + threadIdx.x;
  if (t >= T_TOKENS) return;
  float l[NEXP];
#pragma unroll
  for (int i = 0; i < NEXP; ++i) l[i] = logits[t * NEXP + i];
  int i0 = 0; float b0 = l[0];
#pragma unroll
  for (int i = 1; i < NEXP; ++i) if (l[i] > b0) { b0 = l[i]; i0 = i; }
  int i1 = -1; float b1 = -1e30f;
#pragma unroll
  for (int i = 0; i < NEXP; ++i) if (i != i0 && l[i] > b1) { b1 = l[i]; i1 = i; }
  float e = __expf(b1 - b0);
  float w0 = 1.f / (1.f + e);
  float w1 = e / (1.f + e);
  pe[2 * t] = i0; pe[2 * t + 1] = i1;
  pw[2 * t] = w0; pw[2 * t + 1] = w1;
  atomicAdd(&counts[i0], 1);
  atomicAdd(&counts[i1], 1);
}

// ---------------- scheduler (tiny, single thread) ----------------
__global__ void k_sched(const int* __restrict__ counts, int* cursors,
                        int* ntiles, int* te, int* tr0, int* tcnt) {
  if (threadIdx.x != 0 || blockIdx.x != 0) return;
  int off = 0, nm = 0;
  for (int e = 0; e < NEXP; ++e) {
    int c = counts[e];
    cursors[e] = off;
    for (int m0 = 0; m0 < c; m0 += BM) {
      te[nm] = e;
      tr0[nm] = off + m0;
      tcnt[nm] = min(BM, c - m0);
      ++nm;
    }
    off += c;
  }
  ntiles[0] = nm;
}

// ---------------- scatter: slot assignment ----------------
__global__ void k_scatter(const int* __restrict__ pe, const float* __restrict__ pw,
                          int* cursors, int* rows, float* rw) {
  int t = blockIdx.x * blockDim.x + threadIdx.x;
  if (t >= T_TOKENS) return;
#pragma unroll
  for (int k = 0; k < TOPK; ++k) {
    int e = pe[2 * t + k];
    int s = atomicAdd(&cursors[e], 1);
    rows[s] = t;
    rw[s] = pw[2 * t + k];
  }
}

// ---------------- GEMM1: h0 = X@wi0, h1 = X@wi1, act = silu(h0)*h1 ----------------
__global__ __launch_bounds__(256, 2)
void k_gemm1(const float* __restrict__ X, const float* __restrict__ W0,
             const float* __restrict__ W1, const int* __restrict__ ntiles,
             const int* __restrict__ te, const int* __restrict__ tr0,
             const int* __restrict__ tcnt, const int* __restrict__ rows,
             unsigned short* __restrict__ act) {
  const int ty = blockIdx.y;
  if (ty >= ntiles[0]) return;
  const int e = te[ty], row0 = tr0[ty], mcnt = tcnt[ty];
  const int n0 = blockIdx.x * BN;
  const int tid = threadIdx.x;
  const int lane = tid & 63, wv = tid >> 6;
  const int wr = wv >> 1, wc = wv & 1; // 2x2 waves, 64x64 each

  __shared__ unsigned char sm[49152];
  unsigned char* As = sm;           // [128][64] bf16 swz
  unsigned char* B0s = sm + 16384;  // [128 n][64 k] bf16 swz (transposed)
  unsigned char* B1s = sm + 32768;

  // A staging map: unit c = j*256+tid -> m = c>>4, chunk ch = c&15 (float4)
  int atok[8];
#pragma unroll
  for (int j = 0; j < 8; ++j) {
    int m = (j * 256 + tid) >> 4;
    atok[j] = (m < mcnt) ? rows[row0 + m] : -1;
  }
  // B staging map: n = t0..2 | j<<3 | t7<<6 ; bc(k-chunk) = t3..6
  const int bnb = (tid & 7) | ((tid >> 7) << 6);
  const int bc = (tid >> 3) & 15;

  f32x4 acc0[4][4], acc1[4][4];
  const f32x4 zz = {0.f, 0.f, 0.f, 0.f};
#pragma unroll
  for (int i = 0; i < 4; ++i)
#pragma unroll
    for (int j = 0; j < 4; ++j) { acc0[i][j] = zz; acc1[i][j] = zz; }

  const float* W0e = W0 + (size_t)e * HID * INTER + n0;
  const float* W1e = W1 + (size_t)e * HID * INTER + n0;

  for (int k0 = 0; k0 < HID; k0 += BK) {
    // --- stage A (gathered tokens, f32 -> bf16) ---
#pragma unroll
    for (int j = 0; j < 8; ++j) {
      int c = j * 256 + tid;
      int m = c >> 4, ch = c & 15;
      float4 v = make_float4(0.f, 0.f, 0.f, 0.f);
      int tok = atok[j];
      if (tok >= 0) v = *(const float4*)(X + (size_t)tok * HID + k0 + 4 * ch);
      uint2 p;
      p.x = (unsigned)f2bf(v.x) | ((unsigned)f2bf(v.y) << 16);
      p.y = (unsigned)f2bf(v.z) | ((unsigned)f2bf(v.w) << 16);
      *(uint2*)(As + swz(m, 8 * ch)) = p;
    }
    // --- stage B0/B1 (transposed strided loads, f32 -> bf16) ---
#pragma unroll
    for (int j = 0; j < 8; ++j) {
      int n = bnb | (j << 3);
      const float* p0 = W0e + (size_t)(k0 + 4 * bc) * INTER + n;
      float a0 = p0[0], a1 = p0[INTER], a2 = p0[2 * INTER], a3 = p0[3 * INTER];
      uint2 q;
      q.x = (unsigned)f2bf(a0) | ((unsigned)f2bf(a1) << 16);
      q.y = (unsigned)f2bf(a2) | ((unsigned)f2bf(a3) << 16);
      *(uint2*)(B0s + swz(n, 8 * bc)) = q;
      const float* p1 = W1e + (size_t)(k0 + 4 * bc) * INTER + n;
      a0 = p1[0]; a1 = p1[INTER]; a2 = p1[2 * INTER]; a3 = p1[3 * INTER];
      q.x = (unsigned)f2bf(a0) | ((unsigned)f2bf(a1) << 16);
      q.y = (unsigned)f2bf(a2) | ((unsigned)f2bf(a3) << 16);
      *(uint2*)(B1s + swz(n, 8 * bc)) = q;
    }
    __syncthreads();
    // --- MFMA ---
#pragma unroll
    for (int kq = 0; kq < 2; ++kq) {
      int kb = kq * 64 + 16 * (lane >> 4);
      bf16x8 a[4], b0[4], b1[4];
#pragma unroll
      for (int f = 0; f < 4; ++f) {
        int m = wr * 64 + f * 16 + (lane & 15);
        a[f] = *(const bf16x8*)(As + swz(m, kb));
        int n = wc * 64 + f * 16 + (lane & 15);
        b0[f] = *(const bf16x8*)(B0s + swz(n, kb));
        b1[f] = *(const bf16x8*)(B1s + swz(n, kb));
      }
#pragma unroll
      for (int mf = 0; mf < 4; ++mf)
#pragma unroll
        for (int nf = 0; nf < 4; ++nf) {
          acc0[mf][nf] = __builtin_amdgcn_mfma_f32_16x16x32_bf16(a[mf], b0[nf], acc0[mf][nf], 0, 0, 0);
          acc1[mf][nf] = __builtin_amdgcn_mfma_f32_16x16x32_bf16(a[mf], b1[nf], acc1[mf][nf], 0, 0, 0);
        }
    }
    __syncthreads();
  }
  // --- epilogue: act = silu(h0)*h1, bf16 store ---
#pragma unroll
  for (int mf = 0; mf < 4; ++mf) {
#pragma unroll
    for (int r = 0; r < 4; ++r) {
      int m = wr * 64 + mf * 16 + (lane >> 4) * 4 + r;
      if (m >= mcnt) continue;
      size_t rowbase = (size_t)(row0 + m) * INTER + n0 + wc * 64 + (lane & 15);
#pragma unroll
      for (int nf = 0; nf < 4; ++nf) {
        float h0 = acc0[mf][nf][r];
        float h1 = acc1[mf][nf][r];
        float s = h0 / (1.f + __expf(-h0));
        act[rowbase + nf * 16] = f2bf(s * h1);
      }
    }
  }
}

// ---------------- GEMM2: y = act@wo ; out[token] += w*y ----------------
__global__ __launch_bounds__(256, 2)
void k_gemm2(const unsigned short* __restrict__ act, const float* __restrict__ WO,
             const int* __restrict__ ntiles, const int* __restrict__ te,
             const int* __restrict__ tr0, const int* __restrict__ tcnt,
             const int* __restrict__ rows, const float* __restrict__ rw,
             float* __restrict__ out) {
  const int ty = blockIdx.y;
  if (ty >= ntiles[0]) return;
  const int e = te[ty], row0 = tr0[ty], mcnt = tcnt[ty];
  const int n0 = blockIdx.x * BN;
  const int tid = threadIdx.x;
  const int lane = tid & 63, wv = tid >> 6;
  const int wr = wv >> 1, wc = wv & 1;

  __shared__ unsigned char sm[32768];
  unsigned char* As = sm;          // [128][64] bf16 swz
  unsigned char* Bs = sm + 16384;  // [128 n][64 k] bf16 swz

  const int bnb = (tid & 7) | ((tid >> 7) << 6);
  const int bc = (tid >> 3) & 15;

  f32x4 acc[4][4];
  const f32x4 zz = {0.f, 0.f, 0.f, 0.f};
#pragma unroll
  for (int i = 0; i < 4; ++i)
#pragma unroll
    for (int j = 0; j < 4; ++j) acc[i][j] = zz;

  const float* We = WO + (size_t)e * INTER * HID + n0;

  for (int k0 = 0; k0 < INTER; k0 += BK) {
    // --- stage A (act bf16, direct b128) ---
#pragma unroll
    for (int j = 0; j < 4; ++j) {
      int u = j * 256 + tid;
      int m = u >> 3, ch = u & 7;
      uint4 v = make_uint4(0u, 0u, 0u, 0u);
      if (m < mcnt)
        v = *(const uint4*)(act + (size_t)(row0 + m) * INTER + k0 + 8 * ch);
      *(uint4*)(As + swz(m, 16 * ch)) = v;
    }
    // --- stage B (wo transposed strided, f32 -> bf16) ---
#pragma unroll
    for (int j = 0; j < 8; ++j) {
      int n = bnb | (j << 3);
      const float* p = We + (size_t)(k0 + 4 * bc) * HID + n;
      float a0 = p[0], a1 = p[HID], a2 = p[2 * HID], a3 = p[3 * HID];
      uint2 q;
      q.x = (unsigned)f2bf(a0) | ((unsigned)f2bf(a1) << 16);
      q.y = (unsigned)f2bf(a2) | ((unsigned)f2bf(a3) << 16);
      *(uint2*)(Bs + swz(n, 8 * bc)) = q;
    }
    __syncthreads();
#pragma unroll
    for (int kq = 0; kq < 2; ++kq) {
      int kb = kq * 64 + 16 * (lane >> 4);
      bf16x8 a[4], b[4];
#pragma unroll
      for (int f = 0; f < 4; ++f) {
        int m = wr * 64 + f * 16 + (lane & 15);
        a[f] = *(const bf16x8*)(As + swz(m, kb));
        int n = wc * 64 + f * 16 + (lane & 15);
        b[f] = *(const bf16x8*)(Bs + swz(n, kb));
      }
#pragma unroll
      for (int mf = 0; mf < 4; ++mf)
#pragma unroll
        for (int nf = 0; nf < 4; ++nf)
          acc[mf][nf] = __builtin_amdgcn_mfma_f32_16x16x32_bf16(a[mf], b[nf], acc[mf][nf], 0, 0, 0);
    }
    __syncthreads();
  }
  // --- epilogue: weighted atomic combine ---
#pragma unroll
  for (int mf = 0; mf < 4; ++mf) {
#pragma unroll
    for (int r = 0; r < 4; ++r) {
      int m = wr * 64 + mf * 16 + (lane >> 4) * 4 + r;
      if (m >= mcnt) continue;
      int tok = rows[row0 + m];
      float w = rw[row0 + m];
      float* op = out + (size_t)tok * HID + n0 + wc * 64 + (lane & 15);
#pragma unroll
      for (int nf = 0; nf < 4; ++nf)
        atomicAdd(op + nf * 16, w * acc[mf][nf][r]);
    }
  }
}

extern "C" void kernel_launch(void* const* d_in, const int* in_sizes, int n_in,
                              void* d_out, int out_size, void* d_ws, size_t ws_size,
                              hipStream_t stream) {
  const float* X  = (const float*)d_in[0];
  const float* RL = (const float*)d_in[1];
  const float* W0 = (const float*)d_in[2];
  const float* W1 = (const float*)d_in[3];
  const float* WOp = (const float*)d_in[4];
  float* out = (float*)d_out;

  char* ws = (char*)d_ws;
  int* counts  = (int*)(ws + 0);
  int* cursors = (int*)(ws + 64);
  int* ntiles  = (int*)(ws + 128);
  int* te      = (int*)(ws + 256);
  int* tr0     = (int*)(ws + 768);
  int* tcnt    = (int*)(ws + 1280);
  int* pe      = (int*)(ws + 8192);
  float* pw    = (float*)(ws + 8192 + 32768);
  int* rows    = (int*)(ws + 8192 + 65536);
  float* rw    = (float*)(ws + 8192 + 98304);
  unsigned short* act = (unsigned short*)(ws + (1 << 20));

  hipMemsetAsync(ws, 0, 256, stream);
  hipMemsetAsync(d_out, 0, (size_t)out_size * sizeof(float), stream);

  k_route<<<T_TOKENS / 256, 256, 0, stream>>>(RL, counts, pe, pw);
  k_sched<<<1, 64, 0, stream>>>(counts, cursors, ntiles, te, tr0, tcnt);
  k_scatter<<<T_TOKENS / 256, 256, 0, stream>>>(pe, pw, cursors, rows, rw);
  k_gemm1<<<dim3(INTER / BN, MAXTILES), 256, 0, stream>>>(X, W0, W1, ntiles, te, tr0, tcnt, rows, act);
  k_gemm2<<<dim3(HID / BN, MAXTILES), 256, 0, stream>>>(act, WOp, ntiles, te, tr0, tcnt, rows, rw, out);
}

// Round 2
// 302.482 us; speedup vs baseline: 1.4591x; 1.4591x over previous
//
#include <hip/hip_runtime.h>
#include <hip/hip_bf16.h>

#define T_TOKENS 4096
#define HID 1024
#define INTER 2048
#define NEXP 8
#define TOPK 2
#define RTOT (T_TOKENS * TOPK) /* 8192 */
#define BM 128
#define BN 128
#define BK 64
#define MAXTILES (RTOT / BM + NEXP) /* 72 */

typedef __attribute__((ext_vector_type(8))) short bf16x8;
typedef __attribute__((ext_vector_type(4))) float f32x4;

typedef __attribute__((address_space(1))) const unsigned int gu32;
typedef __attribute__((address_space(3))) unsigned int lu32;

__device__ __forceinline__ void gl16(const void* g, void* l) {
  __builtin_amdgcn_global_load_lds((gu32*)g, (lu32*)l, 16, 0, 0);
}

__device__ __forceinline__ unsigned f2bf(float f) {
  union { float f; unsigned u; } v; v.f = f;
  unsigned u = v.u;
  return (u + 0x7FFFu + ((u >> 16) & 1u)) >> 16;
}

// byte offset in a [128 rows][64 bf16] LDS tile, XOR-swizzled at 16B granularity
__device__ __forceinline__ int swz(int row, int kb) {
  return row * 128 + (kb ^ ((row & 7) << 4));
}

// ---------------- routing ----------------
__global__ void k_route(const float* __restrict__ logits, int* counts,
                        int* pe, float* pw) {
  int t = blockIdx.x * blockDim.x + threadIdx.x;
  if (t >= T_TOKENS) return;
  float l[NEXP];
#pragma unroll
  for (int i = 0; i < NEXP; ++i) l[i] = logits[t * NEXP + i];
  int i0 = 0; float b0 = l[0];
#pragma unroll
  for (int i = 1; i < NEXP; ++i) if (l[i] > b0) { b0 = l[i]; i0 = i; }
  int i1 = -1; float b1 = -1e30f;
#pragma unroll
  for (int i = 0; i < NEXP; ++i) if (i != i0 && l[i] > b1) { b1 = l[i]; i1 = i; }
  float e = __expf(b1 - b0);
  float w0 = 1.f / (1.f + e);
  float w1 = e / (1.f + e);
  pe[2 * t] = i0; pe[2 * t + 1] = i1;
  pw[2 * t] = w0; pw[2 * t + 1] = w1;
  atomicAdd(&counts[i0], 1);
  atomicAdd(&counts[i1], 1);
}

// ---------------- scheduler (tiny, single thread) ----------------
__global__ void k_sched(const int* __restrict__ counts, int* cursors,
                        int* ntiles, int* te, int* tr0, int* tcnt) {
  if (threadIdx.x != 0 || blockIdx.x != 0) return;
  int off = 0, nm = 0;
  for (int e = 0; e < NEXP; ++e) {
    int c = counts[e];
    cursors[e] = off;
    for (int m0 = 0; m0 < c; m0 += BM) {
      te[nm] = e;
      tr0[nm] = off + m0;
      tcnt[nm] = min(BM, c - m0);
      ++nm;
    }
    off += c;
  }
  ntiles[0] = nm;
}

// ---------------- scatter: slot assignment ----------------
__global__ void k_scatter(const int* __restrict__ pe, const float* __restrict__ pw,
                          int* cursors, int* rows, float* rw) {
  int t = blockIdx.x * blockDim.x + threadIdx.x;
  if (t >= T_TOKENS) return;
#pragma unroll
  for (int k = 0; k < TOPK; ++k) {
    int e = pe[2 * t + k];
    int s = atomicAdd(&cursors[e], 1);
    rows[s] = t;
    rw[s] = pw[2 * t + k];
  }
}

// ---------------- X f32 -> bf16 ----------------
__global__ void k_xconv(const float* __restrict__ X, unsigned short* __restrict__ Xb) {
  int i = blockIdx.x * blockDim.x + threadIdx.x; // float4 index
  float4 v = *(const float4*)(X + (size_t)i * 4);
  uint2 p;
  p.x = f2bf(v.x) | (f2bf(v.y) << 16);
  p.y = f2bf(v.z) | (f2bf(v.w) << 16);
  *(uint2*)(Xb + (size_t)i * 4) = p;
}

// ---- weights [E][K][N] f32 -> tiled transposed pre-swizzled bf16 [E][NT][KT][128][64] ----
__global__ __launch_bounds__(256)
void k_wtile(const float* __restrict__ W, unsigned short* __restrict__ out,
             int K, int N) {
  const int kt = blockIdx.x, nt = blockIdx.y, e = blockIdx.z;
  const int KT = gridDim.x, NT = gridDim.y;
  const int tid = threadIdx.x;
  __shared__ float ls[64 * 129];
  const float* src = W + (size_t)e * K * N + (size_t)(kt * 64) * N + nt * 128;
#pragma unroll
  for (int j = 0; j < 8; ++j) {
    int u = j * 256 + tid;
    int k = u >> 5, c4 = u & 31;
    float4 v = *(const float4*)(src + (size_t)k * N + c4 * 4);
    float* d = ls + k * 129 + c4 * 4;
    d[0] = v.x; d[1] = v.y; d[2] = v.z; d[3] = v.w;
  }
  __syncthreads();
  unsigned short* dst = out + ((((size_t)e * NT + nt) * KT + kt) << 13);
#pragma unroll
  for (int j = 0; j < 4; ++j) {
    int v = j * 256 + tid;
    int n = v >> 3, cp = v & 7, c = cp ^ (n & 7);
    const float* col = ls + (c * 8) * 129 + n;
    unsigned b[8];
#pragma unroll
    for (int i = 0; i < 8; ++i) b[i] = f2bf(col[i * 129]);
    uint4 q;
    q.x = b[0] | (b[1] << 16); q.y = b[2] | (b[3] << 16);
    q.z = b[4] | (b[5] << 16); q.w = b[6] | (b[7] << 16);
    *(uint4*)(dst + (size_t)v * 8) = q;
  }
}

// ---------------- GEMM1 (bf16 tiled weights): act = silu(X@W0) * (X@W1) ----------------
__global__ __launch_bounds__(256, 2)
void k_gemm1b(const unsigned short* __restrict__ Xb,
              const unsigned short* __restrict__ WT0,
              const unsigned short* __restrict__ WT1,
              const int* __restrict__ ntiles, const int* __restrict__ te,
              const int* __restrict__ tr0, const int* __restrict__ tcnt,
              const int* __restrict__ rows,
              unsigned short* __restrict__ act) {
  const int ty = blockIdx.y;
  if (ty >= ntiles[0]) return;
  const int e = te[ty], row0 = tr0[ty], mcnt = tcnt[ty];
  const int nt = blockIdx.x;
  const int n0 = nt * BN;
  const int tid = threadIdx.x;
  const int lane = tid & 63, wv = tid >> 6;
  const int wr = wv >> 1, wc = wv & 1;

  __shared__ unsigned char sm[49152];
  unsigned char* As = sm;
  unsigned char* B0s = sm + 16384;
  unsigned char* B1s = sm + 32768;

  // A-gather addressing: chunk u = j*256+tid -> m=u>>3, lds-chunk u&7,
  // global chunk pre-swizzled: (u&7) ^ (m&7)
  int atok[4], acg[4];
#pragma unroll
  for (int j = 0; j < 4; ++j) {
    int u = j * 256 + tid;
    int m = u >> 3;
    atok[j] = rows[row0 + (m < mcnt ? m : mcnt - 1)];
    acg[j] = (u & 7) ^ (m & 7);
  }

  f32x4 acc0[4][4], acc1[4][4];
  const f32x4 zz = {0.f, 0.f, 0.f, 0.f};
#pragma unroll
  for (int i = 0; i < 4; ++i)
#pragma unroll
    for (int j = 0; j < 4; ++j) { acc0[i][j] = zz; acc1[i][j] = zz; }

  const unsigned short* B0t = WT0 + (((size_t)e * 16 + nt) * 16) * 8192;
  const unsigned short* B1t = WT1 + (((size_t)e * 16 + nt) * 16) * 8192;

  for (int kt = 0; kt < HID / BK; ++kt) {
    const int k0 = kt * BK;
    const unsigned short* b0k = B0t + (size_t)kt * 8192;
    const unsigned short* b1k = B1t + (size_t)kt * 8192;
#pragma unroll
    for (int j = 0; j < 4; ++j) {
      const int cb = j * 256 + wv * 64; // wave-uniform LDS chunk base
      gl16(Xb + (size_t)atok[j] * HID + k0 + acg[j] * 8, As + cb * 16);
      gl16(b0k + (size_t)(cb + lane) * 8, B0s + cb * 16);
      gl16(b1k + (size_t)(cb + lane) * 8, B1s + cb * 16);
    }
    __syncthreads();
#pragma unroll
    for (int kq = 0; kq < 2; ++kq) {
      int kb = kq * 64 + 16 * (lane >> 4);
      bf16x8 a[4], b0[4], b1[4];
#pragma unroll
      for (int f = 0; f < 4; ++f) {
        int m = wr * 64 + f * 16 + (lane & 15);
        a[f] = *(const bf16x8*)(As + swz(m, kb));
        int n = wc * 64 + f * 16 + (lane & 15);
        b0[f] = *(const bf16x8*)(B0s + swz(n, kb));
        b1[f] = *(const bf16x8*)(B1s + swz(n, kb));
      }
#pragma unroll
      for (int mf = 0; mf < 4; ++mf)
#pragma unroll
        for (int nf = 0; nf < 4; ++nf) {
          acc0[mf][nf] = __builtin_amdgcn_mfma_f32_16x16x32_bf16(a[mf], b0[nf], acc0[mf][nf], 0, 0, 0);
          acc1[mf][nf] = __builtin_amdgcn_mfma_f32_16x16x32_bf16(a[mf], b1[nf], acc1[mf][nf], 0, 0, 0);
        }
    }
    __syncthreads();
  }
#pragma unroll
  for (int mf = 0; mf < 4; ++mf) {
#pragma unroll
    for (int r = 0; r < 4; ++r) {
      int m = wr * 64 + mf * 16 + (lane >> 4) * 4 + r;
      if (m >= mcnt) continue;
      size_t rowbase = (size_t)(row0 + m) * INTER + n0 + wc * 64 + (lane & 15);
#pragma unroll
      for (int nf = 0; nf < 4; ++nf) {
        float h0 = acc0[mf][nf][r];
        float h1 = acc1[mf][nf][r];
        float s = h0 / (1.f + __expf(-h0));
        act[rowbase + nf * 16] = (unsigned short)f2bf(s * h1);
      }
    }
  }
}

// ---------------- GEMM2 (bf16 tiled weights): out[token] += w * (act@WO) ----------------
__global__ __launch_bounds__(256, 2)
void k_gemm2b(const unsigned short* __restrict__ act,
              const unsigned short* __restrict__ WTo,
              const int* __restrict__ ntiles, const int* __restrict__ te,
              const int* __restrict__ tr0, const int* __restrict__ tcnt,
              const int* __restrict__ rows, const float* __restrict__ rw,
              float* __restrict__ out) {
  const int ty = blockIdx.y;
  if (ty >= ntiles[0]) return;
  const int e = te[ty], row0 = tr0[ty], mcnt = tcnt[ty];
  const int nt = blockIdx.x;
  const int n0 = nt * BN;
  const int tid = threadIdx.x;
  const int lane = tid & 63, wv = tid >> 6;
  const int wr = wv >> 1, wc = wv & 1;

  __shared__ unsigned char sm[32768];
  unsigned char* As = sm;
  unsigned char* Bs = sm + 16384;

  int arow[4], acg[4];
#pragma unroll
  for (int j = 0; j < 4; ++j) {
    int u = j * 256 + tid;
    int m = u >> 3;
    arow[j] = row0 + (m < mcnt ? m : mcnt - 1);
    acg[j] = (u & 7) ^ (m & 7);
  }

  f32x4 acc[4][4];
  const f32x4 zz = {0.f, 0.f, 0.f, 0.f};
#pragma unroll
  for (int i = 0; i < 4; ++i)
#pragma unroll
    for (int j = 0; j < 4; ++j) acc[i][j] = zz;

  const unsigned short* Bt = WTo + (((size_t)e * 8 + nt) * 32) * 8192;

  for (int kt = 0; kt < INTER / BK; ++kt) {
    const int k0 = kt * BK;
    const unsigned short* bk = Bt + (size_t)kt * 8192;
#pragma unroll
    for (int j = 0; j < 4; ++j) {
      const int cb = j * 256 + wv * 64;
      gl16(act + (size_t)arow[j] * INTER + k0 + acg[j] * 8, As + cb * 16);
      gl16(bk + (size_t)(cb + lane) * 8, Bs + cb * 16);
    }
    __syncthreads();
#pragma unroll
    for (int kq = 0; kq < 2; ++kq) {
      int kb = kq * 64 + 16 * (lane >> 4);
      bf16x8 a[4], b[4];
#pragma unroll
      for (int f = 0; f < 4; ++f) {
        int m = wr * 64 + f * 16 + (lane & 15);
        a[f] = *(const bf16x8*)(As + swz(m, kb));
        int n = wc * 64 + f * 16 + (lane & 15);
        b[f] = *(const bf16x8*)(Bs + swz(n, kb));
      }
#pragma unroll
      for (int mf = 0; mf < 4; ++mf)
#pragma unroll
        for (int nf = 0; nf < 4; ++nf)
          acc[mf][nf] = __builtin_amdgcn_mfma_f32_16x16x32_bf16(a[mf], b[nf], acc[mf][nf], 0, 0, 0);
    }
    __syncthreads();
  }
#pragma unroll
  for (int mf = 0; mf < 4; ++mf) {
#pragma unroll
    for (int r = 0; r < 4; ++r) {
      int m = wr * 64 + mf * 16 + (lane >> 4) * 4 + r;
      if (m >= mcnt) continue;
      int tok = rows[row0 + m];
      float w = rw[row0 + m];
      float* op = out + (size_t)tok * HID + n0 + wc * 64 + (lane & 15);
#pragma unroll
      for (int nf = 0; nf < 4; ++nf)
        atomicAdd(op + nf * 16, w * acc[mf][nf][r]);
    }
  }
}

// ================= fallback (round-0) GEMMs, used if ws too small =================
__global__ __launch_bounds__(256, 2)
void k_gemm1_fb(const float* __restrict__ X, const float* __restrict__ W0,
                const float* __restrict__ W1, const int* __restrict__ ntiles,
                const int* __restrict__ te, const int* __restrict__ tr0,
                const int* __restrict__ tcnt, const int* __restrict__ rows,
                unsigned short* __restrict__ act) {
  const int ty = blockIdx.y;
  if (ty >= ntiles[0]) return;
  const int e = te[ty], row0 = tr0[ty], mcnt = tcnt[ty];
  const int n0 = blockIdx.x * BN;
  const int tid = threadIdx.x;
  const int lane = tid & 63, wv = tid >> 6;
  const int wr = wv >> 1, wc = wv & 1;

  __shared__ unsigned char sm[49152];
  unsigned char* As = sm;
  unsigned char* B0s = sm + 16384;
  unsigned char* B1s = sm + 32768;

  int atok[8];
#pragma unroll
  for (int j = 0; j < 8; ++j) {
    int m = (j * 256 + tid) >> 4;
    atok[j] = (m < mcnt) ? rows[row0 + m] : -1;
  }
  const int bnb = (tid & 7) | ((tid >> 7) << 6);
  const int bc = (tid >> 3) & 15;

  f32x4 acc0[4][4], acc1[4][4];
  const f32x4 zz = {0.f, 0.f, 0.f, 0.f};
#pragma unroll
  for (int i = 0; i < 4; ++i)
#pragma unroll
    for (int j = 0; j < 4; ++j) { acc0[i][j] = zz; acc1[i][j] = zz; }

  const float* W0e = W0 + (size_t)e * HID * INTER + n0;
  const float* W1e = W1 + (size_t)e * HID * INTER + n0;

  for (int k0 = 0; k0 < HID; k0 += BK) {
#pragma unroll
    for (int j = 0; j < 8; ++j) {
      int c = j * 256 + tid;
      int m = c >> 4, ch = c & 15;
      float4 v = make_float4(0.f, 0.f, 0.f, 0.f);
      int tok = atok[j];
      if (tok >= 0) v = *(const float4*)(X + (size_t)tok * HID + k0 + 4 * ch);
      uint2 p;
      p.x = f2bf(v.x) | (f2bf(v.y) << 16);
      p.y = f2bf(v.z) | (f2bf(v.w) << 16);
      *(uint2*)(As + swz(m, 8 * ch)) = p;
    }
#pragma unroll
    for (int j = 0; j < 8; ++j) {
      int n = bnb | (j << 3);
      const float* p0 = W0e + (size_t)(k0 + 4 * bc) * INTER + n;
      float a0 = p0[0], a1 = p0[INTER], a2 = p0[2 * INTER], a3 = p0[3 * INTER];
      uint2 q;
      q.x = f2bf(a0) | (f2bf(a1) << 16);
      q.y = f2bf(a2) | (f2bf(a3) << 16);
      *(uint2*)(B0s + swz(n, 8 * bc)) = q;
      const float* p1 = W1e + (size_t)(k0 + 4 * bc) * INTER + n;
      a0 = p1[0]; a1 = p1[INTER]; a2 = p1[2 * INTER]; a3 = p1[3 * INTER];
      q.x = f2bf(a0) | (f2bf(a1) << 16);
      q.y = f2bf(a2) | (f2bf(a3) << 16);
      *(uint2*)(B1s + swz(n, 8 * bc)) = q;
    }
    __syncthreads();
#pragma unroll
    for (int kq = 0; kq < 2; ++kq) {
      int kb = kq * 64 + 16 * (lane >> 4);
      bf16x8 a[4], b0[4], b1[4];
#pragma unroll
      for (int f = 0; f < 4; ++f) {
        int m = wr * 64 + f * 16 + (lane & 15);
        a[f] = *(const bf16x8*)(As + swz(m, kb));
        int n = wc * 64 + f * 16 + (lane & 15);
        b0[f] = *(const bf16x8*)(B0s + swz(n, kb));
        b1[f] = *(const bf16x8*)(B1s + swz(n, kb));
      }
#pragma unroll
      for (int mf = 0; mf < 4; ++mf)
#pragma unroll
        for (int nf = 0; nf < 4; ++nf) {
          acc0[mf][nf] = __builtin_amdgcn_mfma_f32_16x16x32_bf16(a[mf], b0[nf], acc0[mf][nf], 0, 0, 0);
          acc1[mf][nf] = __builtin_amdgcn_mfma_f32_16x16x32_bf16(a[mf], b1[nf], acc1[mf][nf], 0, 0, 0);
        }
    }
    __syncthreads();
  }
#pragma unroll
  for (int mf = 0; mf < 4; ++mf) {
#pragma unroll
    for (int r = 0; r < 4; ++r) {
      int m = wr * 64 + mf * 16 + (lane >> 4) * 4 + r;
      if (m >= mcnt) continue;
      size_t rowbase = (size_t)(row0 + m) * INTER + n0 + wc * 64 + (lane & 15);
#pragma unroll
      for (int nf = 0; nf < 4; ++nf) {
        float h0 = acc0[mf][nf][r];
        float h1 = acc1[mf][nf][r];
        float s = h0 / (1.f + __expf(-h0));
        act[rowbase + nf * 16] = (unsigned short)f2bf(s * h1);
      }
    }
  }
}

__global__ __launch_bounds__(256, 2)
void k_gemm2_fb(const unsigned short* __restrict__ act, const float* __restrict__ WO,
                const int* __restrict__ ntiles, const int* __restrict__ te,
                const int* __restrict__ tr0, const int* __restrict__ tcnt,
                const int* __restrict__ rows, const float* __restrict__ rw,
                float* __restrict__ out) {
  const int ty = blockIdx.y;
  if (ty >= ntiles[0]) return;
  const int e = te[ty], row0 = tr0[ty], mcnt = tcnt[ty];
  const int n0 = blockIdx.x * BN;
  const int tid = threadIdx.x;
  const int lane = tid & 63, wv = tid >> 6;
  const int wr = wv >> 1, wc = wv & 1;

  __shared__ unsigned char sm[32768];
  unsigned char* As = sm;
  unsigned char* Bs = sm + 16384;

  const int bnb = (tid & 7) | ((tid >> 7) << 6);
  const int bc = (tid >> 3) & 15;

  f32x4 acc[4][4];
  const f32x4 zz = {0.f, 0.f, 0.f, 0.f};
#pragma unroll
  for (int i = 0; i < 4; ++i)
#pragma unroll
    for (int j = 0; j < 4; ++j) acc[i][j] = zz;

  const float* We = WO + (size_t)e * INTER * HID + n0;

  for (int k0 = 0; k0 < INTER; k0 += BK) {
#pragma unroll
    for (int j = 0; j < 4; ++j) {
      int u = j * 256 + tid;
      int m = u >> 3, ch = u & 7;
      uint4 v = make_uint4(0u, 0u, 0u, 0u);
      if (m < mcnt)
        v = *(const uint4*)(act + (size_t)(row0 + m) * INTER + k0 + 8 * ch);
      *(uint4*)(As + swz(m, 16 * ch)) = v;
    }
#pragma unroll
    for (int j = 0; j < 8; ++j) {
      int n = bnb | (j << 3);
      const float* p = We + (size_t)(k0 + 4 * bc) * HID + n;
      float a0 = p[0], a1 = p[HID], a2 = p[2 * HID], a3 = p[3 * HID];
      uint2 q;
      q.x = f2bf(a0) | (f2bf(a1) << 16);
      q.y = f2bf(a2) | (f2bf(a3) << 16);
      *(uint2*)(Bs + swz(n, 8 * bc)) = q;
    }
    __syncthreads();
#pragma unroll
    for (int kq = 0; kq < 2; ++kq) {
      int kb = kq * 64 + 16 * (lane >> 4);
      bf16x8 a[4], b[4];
#pragma unroll
      for (int f = 0; f < 4; ++f) {
        int m = wr * 64 + f * 16 + (lane & 15);
        a[f] = *(const bf16x8*)(As + swz(m, kb));
        int n = wc * 64 + f * 16 + (lane & 15);
        b[f] = *(const bf16x8*)(Bs + swz(n, kb));
      }
#pragma unroll
      for (int mf = 0; mf < 4; ++mf)
#pragma unroll
        for (int nf = 0; nf < 4; ++nf)
          acc[mf][nf] = __builtin_amdgcn_mfma_f32_16x16x32_bf16(a[mf], b[nf], acc[mf][nf], 0, 0, 0);
    }
    __syncthreads();
  }
#pragma unroll
  for (int mf = 0; mf < 4; ++mf) {
#pragma unroll
    for (int r = 0; r < 4; ++r) {
      int m = wr * 64 + mf * 16 + (lane >> 4) * 4 + r;
      if (m >= mcnt) continue;
      int tok = rows[row0 + m];
      float w = rw[row0 + m];
      float* op = out + (size_t)tok * HID + n0 + wc * 64 + (lane & 15);
#pragma unroll
      for (int nf = 0; nf < 4; ++nf)
        atomicAdd(op + nf * 16, w * acc[mf][nf][r]);
    }
  }
}

extern "C" void kernel_launch(void* const* d_in, const int* in_sizes, int n_in,
                              void* d_out, int out_size, void* d_ws, size_t ws_size,
                              hipStream_t stream) {
  const float* X  = (const float*)d_in[0];
  const float* RL = (const float*)d_in[1];
  const float* W0 = (const float*)d_in[2];
  const float* W1 = (const float*)d_in[3];
  const float* WOp = (const float*)d_in[4];
  float* out = (float*)d_out;

  char* ws = (char*)d_ws;
  int* counts  = (int*)(ws + 0);
  int* cursors = (int*)(ws + 64);
  int* ntiles  = (int*)(ws + 128);
  int* te      = (int*)(ws + 256);
  int* tr0     = (int*)(ws + 768);
  int* tcnt    = (int*)(ws + 1280);
  int* pe      = (int*)(ws + 8192);
  float* pw    = (float*)(ws + 8192 + 32768);
  int* rows    = (int*)(ws + 8192 + 65536);
  float* rw    = (float*)(ws + 8192 + 98304);

  hipMemsetAsync(ws, 0, 256, stream);
  hipMemsetAsync(d_out, 0, (size_t)out_size * sizeof(float), stream);

  k_route<<<T_TOKENS / 256, 256, 0, stream>>>(RL, counts, pe, pw);
  k_sched<<<1, 64, 0, stream>>>(counts, cursors, ntiles, te, tr0, tcnt);
  k_scatter<<<T_TOKENS / 256, 256, 0, stream>>>(pe, pw, cursors, rows, rw);

  const bool big = ws_size >= ((size_t)145 << 20);
  if (big) {
    unsigned short* Xb  = (unsigned short*)(ws + ((size_t)1 << 20));   // 8 MB
    unsigned short* act = (unsigned short*)(ws + ((size_t)16 << 20));  // 32 MB
    unsigned short* WT0 = (unsigned short*)(ws + ((size_t)48 << 20));  // 32 MB
    unsigned short* WT1 = (unsigned short*)(ws + ((size_t)80 << 20));  // 32 MB
    unsigned short* WTo = (unsigned short*)(ws + ((size_t)112 << 20)); // 32 MB

    k_xconv<<<(T_TOKENS * HID / 4) / 256, 256, 0, stream>>>(X, Xb);
    k_wtile<<<dim3(HID / 64, INTER / 128, NEXP), 256, 0, stream>>>(W0, WT0, HID, INTER);
    k_wtile<<<dim3(HID / 64, INTER / 128, NEXP), 256, 0, stream>>>(W1, WT1, HID, INTER);
    k_wtile<<<dim3(INTER / 64, HID / 128, NEXP), 256, 0, stream>>>(WOp, WTo, INTER, HID);

    k_gemm1b<<<dim3(INTER / BN, MAXTILES), 256, 0, stream>>>(Xb, WT0, WT1, ntiles, te, tr0, tcnt, rows, act);
    k_gemm2b<<<dim3(HID / BN, MAXTILES), 256, 0, stream>>>(act, WTo, ntiles, te, tr0, tcnt, rows, rw, out);
  } else {
    unsigned short* act = (unsigned short*)(ws + ((size_t)1 << 20));
    k_gemm1_fb<<<dim3(INTER / BN, MAXTILES), 256, 0, stream>>>(X, W0, W1, ntiles, te, tr0, tcnt, rows, act);
    k_gemm2_fb<<<dim3(HID / BN, MAXTILES), 256, 0, stream>>>(act, WOp, ntiles, te, tr0, tcnt, rows, rw, out);
  }
}